// Round 9
// baseline (219.388 us; speedup 1.0000x reference)
//
#include <hip/hip_runtime.h>
#include <hip/hip_bf16.h>

// AKConv fp32 in/out, bf16 MFMA everywhere.
//  k_prep  : fused {BN fold + A-frag pre-swizzles} U {x -> xT/xTlo channel-last}
//  k_offset: 3x3 offset conv as double-bf16 MFMA GEMM + bilinear tables
//            (4 waves/block for apw L1 reuse). idx4 = packed (row<<16)|col.
//  k_main  : fused gather + MFMA GEMM (M=256,K=640,N=51200) + BN + SiLU.
//            Tile N=64 = 4x16 px. LDS pixel-patch (8x19 rows, 272B stride)
//            deduplicates bilinear corner fetches (4.1M -> ~0.5M lines);
//            per-thread global fallback keeps correctness for |off|>=1.

typedef __attribute__((ext_vector_type(8))) short short8;
typedef __attribute__((ext_vector_type(4))) float f32x4;

#define Bsz 8
#define C1 128
#define C2 256
#define HW 6400
#define NP 5
#define PSTRIDE 272            // patch slot stride bytes (256 data + 16 pad)

// ---- workspace layout (bytes) ----
#define NPOS (Bsz*NP*HW)
#define WS_IDX4 0                           // int4[NPOS]: packed (r<<16)|c per corner
#define WS_WGT4 (WS_IDX4 + NPOS*16)         // float4[NPOS]
#define WS_XT   (WS_WGT4 + NPOS*16)         // ushort xT[8][6400][128]   13.1 MB
#define WS_XTLO (WS_XT + Bsz*HW*C1*2)       // ushort xTlo[...]          13.1 MB
#define WS_ACW  (WS_XTLO + Bsz*HW*C1*2)     // ushort acw[163840]
#define WS_APWH (WS_ACW + C2*C1*NP*2)       // ushort apw_hi[18432]
#define WS_APWL (WS_APWH + 18432*2)         // ushort apw_lo[18432]
#define WS_BNS  (WS_APWL + 18432*2)
#define WS_BNT  (WS_BNS + 1024)

__device__ __forceinline__ unsigned short f2bf(float f) {
  __hip_bfloat16 h = __float2bfloat16(f);
  return reinterpret_cast<unsigned short&>(h);
}
__device__ __forceinline__ float bfu2f(unsigned short u) {
  unsigned int v = ((unsigned int)u) << 16;
  return reinterpret_cast<float&>(v);
}

// ---- K0: fused pre-swizzle (blocks 0..711) + transpose (blocks 712..2311) ---
__global__ __launch_bounds__(256) void k_prep(
    const float* __restrict__ x, const float* __restrict__ cw,
    const float* __restrict__ pw,
    const float* __restrict__ gam, const float* __restrict__ bet,
    const float* __restrict__ mu, const float* __restrict__ var,
    unsigned short* __restrict__ xT, unsigned short* __restrict__ xTlo,
    unsigned short* __restrict__ acw, unsigned short* __restrict__ apwh,
    unsigned short* __restrict__ apwl,
    float* __restrict__ bns, float* __restrict__ bnt) {
  __shared__ float lds[128][33];
  int t = threadIdx.x;
  if (blockIdx.x < 712) {
    int i = blockIdx.x * 256 + t;
    if (i < 163840) {
      int j = i & 7, lane = (i >> 3) & 63, mtile = (i >> 9) & 15;
      int cc = (i >> 13) & 3, k = i >> 15;
      int m = mtile * 16 + (lane & 15);
      int c = cc * 32 + (lane >> 4) * 8 + j;
      acw[i] = f2bf(cw[(m * C1 + c) * NP + k]);
    } else {
      int i2 = i - 163840;
      int j = i2 & 7, lane = (i2 >> 3) & 63, chunk = i2 >> 9;
      int m = lane & 15, tap = chunk >> 2;
      int c = (chunk & 3) * 32 + (lane >> 4) * 8 + j;
      float wv = (m < 10) ? pw[(m * C1 + c) * 9 + tap] : 0.f;
      unsigned short hi = f2bf(wv);
      apwh[i2] = hi;
      apwl[i2] = f2bf(wv - bfu2f(hi));
    }
    if (blockIdx.x == 0) {
      float s = gam[t] * rsqrtf(var[t] + 1e-5f);
      bns[t] = s;
      bnt[t] = bet[t] - mu[t] * s;
    }
    return;
  }
  int gp0 = (blockIdx.x - 712) * 32;
  int b = gp0 / HW, p0 = gp0 - b * HW;
  const float* xb = x + (size_t)b * C1 * HW;
  int q = t & 7, r = t >> 3;
#pragma unroll
  for (int pass = 0; pass < 4; ++pass) {
    int c = pass * 32 + r;
    float4 v = *(const float4*)(xb + (size_t)c * HW + p0 + q * 4);
    lds[c][q * 4 + 0] = v.x;
    lds[c][q * 4 + 1] = v.y;
    lds[c][q * 4 + 2] = v.z;
    lds[c][q * 4 + 3] = v.w;
  }
  __syncthreads();
  int px = t >> 3, u = t & 7;
#pragma unroll
  for (int it = 0; it < 2; ++it) {
    int unit = it * 8 + u;
    int c0 = unit * 8;
    unsigned short vh[8], vl[8];
#pragma unroll
    for (int e = 0; e < 8; ++e) {
      float f = lds[c0 + e][px];
      unsigned short h = f2bf(f);
      vh[e] = h;
      vl[e] = f2bf(f - bfu2f(h));
    }
    size_t base = (size_t)(gp0 + px) * C1 + unit * 8;
    *(uint4*)(xT + base) = *(uint4*)vh;
    *(uint4*)(xTlo + base) = *(uint4*)vl;
  }
}

// ---- K1: offset conv via double-bf16 MFMA + bilinear tables ----------------
// 4 waves/block (co-scheduled waves reuse the apw stream in L1), 800 blocks.
__global__ __launch_bounds__(256) void k_offset(
    const unsigned short* __restrict__ xT, const unsigned short* __restrict__ xTlo,
    const unsigned short* __restrict__ apwh, const unsigned short* __restrict__ apwl,
    const float* __restrict__ pb,
    int4* __restrict__ idx4, float4* __restrict__ wgt4) {
  __shared__ float sOff[4][10][16];
  int t = threadIdx.x, wave = t >> 6, lane = t & 63;
  int n16 = lane & 15, koct = lane >> 4;
  int gp = blockIdx.x * 64 + wave * 16 + n16;
  int b = gp / HW, p = gp - b * HW;
  int h = p / 80, w = p - h * 80;
  const char* xTb = (const char*)xT + (size_t)b * HW * 256;
  const char* xTlb = (const char*)xTlo + (size_t)b * HW * 256;

  f32x4 acc = (f32x4)(0.f);
#pragma unroll
  for (int chunk = 0; chunk < 36; ++chunk) {
    int tap = chunk >> 2, cc = chunk & 3;
    int dh = tap / 3 - 1, dw = tap - (tap / 3) * 3 - 1;
    int hh = h + dh, ww = w + dw;
    bool ok = ((unsigned)hh < 80u) && ((unsigned)ww < 80u);
    short8 bh = 0, bl = 0;
    if (ok) {
      int boff = ((hh * 80 + ww) << 8) + cc * 64 + koct * 16;
      bh = *(const short8*)(xTb + boff);
      bl = *(const short8*)(xTlb + boff);
    }
    short8 ah = *(const short8*)(apwh + (chunk * 64 + lane) * 8);
    short8 al = *(const short8*)(apwl + (chunk * 64 + lane) * 8);
    acc = __builtin_amdgcn_mfma_f32_16x16x32_bf16(ah, bh, acc, 0, 0, 0);
    acc = __builtin_amdgcn_mfma_f32_16x16x32_bf16(ah, bl, acc, 0, 0, 0);
    acc = __builtin_amdgcn_mfma_f32_16x16x32_bf16(al, bh, acc, 0, 0, 0);
  }

  int quad = lane >> 4;
#pragma unroll
  for (int r = 0; r < 4; ++r) {
    int row = quad * 4 + r;
    if (row < 10) sOff[wave][row][n16] = acc[r];
  }
  __syncthreads();

  for (int task = t; task < 320; task += 256) {
    int wv = task / 80, rem = task - wv * 80, k = rem >> 4, n = rem & 15;
    int gp2 = blockIdx.x * 64 + wv * 16 + n;
    int b2 = gp2 / HW, p2 = gp2 - b2 * HW;
    int h2 = p2 / 80, w2 = p2 - h2 * 80;
    float px = sOff[wv][k][n] + pb[k] + (float)(h2 + (k >> 1));
    float py = sOff[wv][5 + k][n] + pb[5 + k] + (float)(w2 + (k & 1));
    float pf = floorf(px), qf = floorf(py);
    float x0 = fminf(fmaxf(pf, 0.f), 79.f);
    float x1 = fminf(fmaxf(pf + 1.f, 0.f), 79.f);
    float y0 = fminf(fmaxf(qf, 0.f), 79.f);
    float y1 = fminf(fmaxf(qf + 1.f, 0.f), 79.f);
    float pxc = fminf(fmaxf(px, 0.f), 79.f);
    float pyc = fminf(fmaxf(py, 0.f), 79.f);
    float wx0 = 1.f + (x0 - pxc), wx1 = 1.f - (x1 - pxc);
    float wy0 = 1.f + (y0 - pyc), wy1 = 1.f - (y1 - pyc);
    int ix0 = (int)x0, ix1 = (int)x1, iy0 = (int)y0, iy1 = (int)y1;
    int g = (b2 * NP + k) * HW + p2;
    idx4[g] = make_int4((ix0 << 16) | iy0, (ix1 << 16) | iy1,
                        (ix0 << 16) | iy1, (ix1 << 16) | iy0);
    wgt4[g] = make_float4(wx0 * wy0, wx1 * wy1, wx0 * wy1, wx1 * wy0);
  }
}

// ---- K3: patch-deduplicated gather + MFMA GEMM + BN + SiLU -----------------
// Staging thread (o=t&3, s=t>>2): sample s of the 4x16 tile, channel-octet o.
// Corners read from LDS patch when inside (common), else global fallback.
__device__ __forceinline__ void stage_k(
    const char* patchL, const char* xTb,
    const int4* __restrict__ idx4, const float4* __restrict__ wgt4,
    unsigned short* BsBuf, size_t gbase, int spix,
    int r0, int c0, int nr, int nc, int so, int ss) {
  int4 rc = idx4[gbase + spix];
  float4 wg = wgt4[gbase + spix];
  int rcv[4] = {rc.x, rc.y, rc.z, rc.w};
  int la[4], ga[4];
  bool allin = true;
#pragma unroll
  for (int j = 0; j < 4; ++j) {
    int r = rcv[j] >> 16, c = rcv[j] & 0xffff;
    int pr = r - r0, pc = c - c0;
    allin &= ((unsigned)pr < (unsigned)nr) && ((unsigned)pc < (unsigned)nc);
    la[j] = (pr * 19 + pc) * PSTRIDE;
    ga[j] = (r * 80 + c) << 8;
  }
  int grp = ss >> 4, l2 = (so << 4) | (ss & 15);
#pragma unroll
  for (int cc = 0; cc < 4; ++cc) {
    int cb = cc * 64 + so * 16;
    uint4 q0, q1, q2, q3;
    if (allin) {
      q0 = *(const uint4*)(patchL + la[0] + cb);
      q1 = *(const uint4*)(patchL + la[1] + cb);
      q2 = *(const uint4*)(patchL + la[2] + cb);
      q3 = *(const uint4*)(patchL + la[3] + cb);
    } else {
      q0 = *(const uint4*)(xTb + ga[0] + cb);
      q1 = *(const uint4*)(xTb + ga[1] + cb);
      q2 = *(const uint4*)(xTb + ga[2] + cb);
      q3 = *(const uint4*)(xTb + ga[3] + cb);
    }
    union { uint4 v; unsigned short u[8]; } a0, a1, a2, a3, rr;
    a0.v = q0; a1.v = q1; a2.v = q2; a3.v = q3;
#pragma unroll
    for (int e = 0; e < 8; ++e) {
      float f = wg.x * bfu2f(a0.u[e]) + wg.y * bfu2f(a1.u[e])
              + wg.z * bfu2f(a2.u[e]) + wg.w * bfu2f(a3.u[e]);
      rr.u[e] = f2bf(f);
    }
    *(uint4*)&BsBuf[((cc * 4 + grp) * 64 + l2) * 8] = rr.v;
  }
}

__global__ __launch_bounds__(256) void k_main(
    const unsigned short* __restrict__ xT,
    const unsigned short* __restrict__ acw,
    const int4* __restrict__ idx4, const float4* __restrict__ wgt4,
    const float* __restrict__ bns, const float* __restrict__ bnt,
    float* __restrict__ out) {
  __shared__ char patchL[152 * PSTRIDE];           // 41,344 B (8 x 19 pixel rows)
  __shared__ unsigned short Bs[2][16 * 64 * 8];    // 2 x 16 KB

  int t = threadIdx.x;
  int blk = blockIdx.x;                  // 800 = 8b x 20tr x 5tc
  int b = blk / 100;
  int rem = blk - b * 100;
  int h0 = (rem / 5) * 4, w0 = (rem % 5) * 16;
  int r0 = max(0, h0 - 1), r1 = min(79, h0 + 6);
  int c0 = max(0, w0 - 1), c1 = min(79, w0 + 17);
  int nr = r1 - r0 + 1, nc = c1 - c0 + 1;
  const char* xTb = (const char*)xT + (size_t)b * HW * 256;

  // ---- stage pixel patch (coalesced row runs)
  for (int pr = 0; pr < nr; ++pr) {
    const char* src = xTb + (((r0 + pr) * 80 + c0) << 8);
    char* dst = patchL + pr * 19 * PSTRIDE;
    int units = nc * 16;
    for (int u = t; u < units; u += 256) {
      int pc = u >> 4, cb = (u & 15) * 16;
      *(uint4*)(dst + pc * PSTRIDE + cb) = *(const uint4*)(src + (pc << 8) + cb);
    }
  }

  int wave = t >> 6, lane = t & 63;
  int so = t & 3, ss = t >> 2;
  int spix = (h0 + (ss >> 4)) * 80 + w0 + (ss & 15);
  size_t bNP = (size_t)b * NP;

  f32x4 acc[4][4];
#pragma unroll
  for (int mt = 0; mt < 4; ++mt)
#pragma unroll
    for (int nt = 0; nt < 4; ++nt) acc[mt][nt] = (f32x4)(0.f);

  __syncthreads();                       // patch ready
  stage_k(patchL, xTb, idx4, wgt4, Bs[0], bNP * HW, spix, r0, c0, nr, nc, so, ss);

#pragma unroll
  for (int k = 0; k < NP; ++k) {
    __syncthreads();                     // Bs[k&1] staged for all waves
    if (k + 1 < NP)
      stage_k(patchL, xTb, idx4, wgt4, Bs[(k + 1) & 1],
              (bNP + k + 1) * HW, spix, r0, c0, nr, nc, so, ss);
    const unsigned short* Bk = Bs[k & 1];
#pragma unroll
    for (int cc = 0; cc < 4; ++cc) {
      short8 bfr[4];
#pragma unroll
      for (int nt = 0; nt < 4; ++nt)
        bfr[nt] = *(const short8*)&Bk[((cc * 4 + nt) * 64 + lane) * 8];
      const unsigned short* ab =
          acw + (size_t)((((k * 4 + cc) * 16) + wave * 4) * 64 + lane) * 8;
#pragma unroll
      for (int mt = 0; mt < 4; ++mt) {
        short8 a = *(const short8*)(ab + mt * 64 * 8);
#pragma unroll
        for (int nt = 0; nt < 4; ++nt)
          acc[mt][nt] = __builtin_amdgcn_mfma_f32_16x16x32_bf16(
              a, bfr[nt], acc[mt][nt], 0, 0, 0);
      }
    }
  }

  // ---- epilogue: BN + SiLU; group nt = tile row, col = pixel within row
  int quad = lane >> 4, col = lane & 15;
#pragma unroll
  for (int mt = 0; mt < 4; ++mt) {
    int m0 = wave * 64 + mt * 16 + quad * 4;
#pragma unroll
    for (int r = 0; r < 4; ++r) {
      int m = m0 + r;
      float s = bns[m], sh = bnt[m];
      float* op = out + ((size_t)(b * C2 + m)) * HW + h0 * 80 + w0;
#pragma unroll
      for (int nt = 0; nt < 4; ++nt) {
        float y = fmaf(acc[mt][nt][r], s, sh);
        op[nt * 80 + col] = y * (1.f / (1.f + __expf(-y)));
      }
    }
  }
}

extern "C" void kernel_launch(void* const* d_in, const int* in_sizes, int n_in,
                              void* d_out, int out_size, void* d_ws, size_t ws_size,
                              hipStream_t stream) {
  const float* x  = (const float*)d_in[0];
  const float* pw = (const float*)d_in[1];
  const float* pb = (const float*)d_in[2];
  const float* cw = (const float*)d_in[3];
  const float* bg = (const float*)d_in[4];
  const float* bb = (const float*)d_in[5];
  const float* bm = (const float*)d_in[6];
  const float* bv = (const float*)d_in[7];
  float* out = (float*)d_out;

  char* ws = (char*)d_ws;
  int4*           idx4 = (int4*)(ws + WS_IDX4);
  float4*         wgt4 = (float4*)(ws + WS_WGT4);
  unsigned short* xT   = (unsigned short*)(ws + WS_XT);
  unsigned short* xTlo = (unsigned short*)(ws + WS_XTLO);
  unsigned short* acw  = (unsigned short*)(ws + WS_ACW);
  unsigned short* apwh = (unsigned short*)(ws + WS_APWH);
  unsigned short* apwl = (unsigned short*)(ws + WS_APWL);
  float*          bns  = (float*)(ws + WS_BNS);
  float*          bnt  = (float*)(ws + WS_BNT);

  k_prep<<<2312, 256, 0, stream>>>(x, cw, pw, bg, bb, bm, bv,
                                   xT, xTlo, acw, apwh, apwl, bns, bnt);
  k_offset<<<800, 256, 0, stream>>>(xT, xTlo, apwh, apwl, pb, idx4, wgt4);
  k_main<<<800, 256, 0, stream>>>(xT, acw, idx4, wgt4, bns, bnt, out);
}

// Round 11
// 178.471 us; speedup vs baseline: 1.2293x; 1.2293x over previous
//
#include <hip/hip_runtime.h>
#include <hip/hip_bf16.h>

// AKConv fp32 in/out, bf16 MFMA everywhere.
//  k_prep  : fused {BN fold + A-frag pre-swizzles} U {x -> xT/xTlo channel-last}
//  k_offset: 3x3 offset conv via double-bf16 MFMA with LDS-tiled pixel patch
//            (6x18 rows per 32-ch chunk; 9x tap re-reads served from LDS;
//            x-traffic 460->88 MB) + bilinear idx/wgt tables to global.
//  k_main  : R7-verified gather + MFMA GEMM (M=256,K=640,N=51200) + BN + SiLU.

typedef __attribute__((ext_vector_type(8))) short short8;
typedef __attribute__((ext_vector_type(4))) float f32x4;

#define Bsz 8
#define C1 128
#define C2 256
#define HW 6400
#define NP 5

// ---- workspace layout (bytes) ----
#define NPOS (Bsz*NP*HW)                    // 256000 samples
#define WS_IDX4 0                           // int4[NPOS]: corner BYTE offsets into xT image
#define WS_WGT4 (WS_IDX4 + NPOS*16)         // float4[NPOS]
#define WS_XT   (WS_WGT4 + NPOS*16)         // ushort xT[8][6400][128]   13.1 MB (hi)
#define WS_XTLO (WS_XT + Bsz*HW*C1*2)       // ushort xTlo[...]          13.1 MB (residual)
#define WS_ACW  (WS_XTLO + Bsz*HW*C1*2)     // ushort acw[163840]
#define WS_APWH (WS_ACW + C2*C1*NP*2)       // ushort apw_hi[18432]
#define WS_APWL (WS_APWH + 18432*2)         // ushort apw_lo[18432]
#define WS_BNS  (WS_APWL + 18432*2)
#define WS_BNT  (WS_BNS + 1024)

__device__ __forceinline__ unsigned short f2bf(float f) {
  __hip_bfloat16 h = __float2bfloat16(f);
  return reinterpret_cast<unsigned short&>(h);
}
__device__ __forceinline__ float bfu2f(unsigned short u) {
  unsigned int v = ((unsigned int)u) << 16;
  return reinterpret_cast<float&>(v);
}

// ---- K0: fused pre-swizzle (blocks 0..711) + transpose (blocks 712..2311) ---
__global__ __launch_bounds__(256) void k_prep(
    const float* __restrict__ x, const float* __restrict__ cw,
    const float* __restrict__ pw,
    const float* __restrict__ gam, const float* __restrict__ bet,
    const float* __restrict__ mu, const float* __restrict__ var,
    unsigned short* __restrict__ xT, unsigned short* __restrict__ xTlo,
    unsigned short* __restrict__ acw, unsigned short* __restrict__ apwh,
    unsigned short* __restrict__ apwl,
    float* __restrict__ bns, float* __restrict__ bnt) {
  __shared__ float lds[128][33];
  int t = threadIdx.x;
  if (blockIdx.x < 712) {
    int i = blockIdx.x * 256 + t;
    if (i < 163840) {
      int j = i & 7, lane = (i >> 3) & 63, mtile = (i >> 9) & 15;
      int cc = (i >> 13) & 3, k = i >> 15;
      int m = mtile * 16 + (lane & 15);
      int c = cc * 32 + (lane >> 4) * 8 + j;
      acw[i] = f2bf(cw[(m * C1 + c) * NP + k]);
    } else {
      int i2 = i - 163840;
      int j = i2 & 7, lane = (i2 >> 3) & 63, chunk = i2 >> 9;
      int m = lane & 15, tap = chunk >> 2;
      int c = (chunk & 3) * 32 + (lane >> 4) * 8 + j;
      float wv = (m < 10) ? pw[(m * C1 + c) * 9 + tap] : 0.f;
      unsigned short hi = f2bf(wv);
      apwh[i2] = hi;
      apwl[i2] = f2bf(wv - bfu2f(hi));
    }
    if (blockIdx.x == 0) {
      float s = gam[t] * rsqrtf(var[t] + 1e-5f);
      bns[t] = s;
      bnt[t] = bet[t] - mu[t] * s;
    }
    return;
  }
  int gp0 = (blockIdx.x - 712) * 32;
  int b = gp0 / HW, p0 = gp0 - b * HW;
  const float* xb = x + (size_t)b * C1 * HW;
  int q = t & 7, r = t >> 3;
#pragma unroll
  for (int pass = 0; pass < 4; ++pass) {
    int c = pass * 32 + r;
    float4 v = *(const float4*)(xb + (size_t)c * HW + p0 + q * 4);
    lds[c][q * 4 + 0] = v.x;
    lds[c][q * 4 + 1] = v.y;
    lds[c][q * 4 + 2] = v.z;
    lds[c][q * 4 + 3] = v.w;
  }
  __syncthreads();
  int px = t >> 3, u = t & 7;
#pragma unroll
  for (int it = 0; it < 2; ++it) {
    int unit = it * 8 + u;
    int c0 = unit * 8;
    unsigned short vh[8], vl[8];
#pragma unroll
    for (int e = 0; e < 8; ++e) {
      float f = lds[c0 + e][px];
      unsigned short h = f2bf(f);
      vh[e] = h;
      vl[e] = f2bf(f - bfu2f(h));
    }
    size_t base = (size_t)(gp0 + px) * C1 + unit * 8;
    *(uint4*)(xT + base) = *(uint4*)vh;
    *(uint4*)(xTlo + base) = *(uint4*)vl;
  }
}

// ---- K1: offset conv via double-bf16 MFMA + LDS pixel patch ---------------
// Block = 64-px tile (4 rows x 16 cols), wave = tile row. Per cc chunk (32 ch):
// stage 6x18 patch (hi+lo, zero-filled at borders) into LDS once, then 9 taps
// x 3 MFMAs read from LDS. Patch slot stride 80 B (16B-aligned, conflict-lite).
__global__ __launch_bounds__(256) void k_offset(
    const unsigned short* __restrict__ xT, const unsigned short* __restrict__ xTlo,
    const unsigned short* __restrict__ apwh, const unsigned short* __restrict__ apwl,
    const float* __restrict__ pb,
    int4* __restrict__ idx4, float4* __restrict__ wgt4) {
  __shared__ __align__(16) char patch[2 * 6 * 18 * 80];   // 17,280 B
  __shared__ float sOff[4][10][16];

  int t = threadIdx.x, wave = t >> 6, lane = t & 63;
  int n16 = lane & 15, koct = lane >> 4;
  int blk = blockIdx.x;                            // 800 = 8b x 20tr x 5tc
  int b = blk / 100;
  int rem = blk - b * 100;
  int h0 = (rem / 5) * 4, w0 = (rem % 5) * 16;
  const char* xTb  = (const char*)xT  + (size_t)b * HW * 256;
  const char* xTlb = (const char*)xTlo + (size_t)b * HW * 256;

  f32x4 acc = (f32x4)(0.f);
#pragma unroll
  for (int cc = 0; cc < 4; ++cc) {
    __syncthreads();                               // patch free to overwrite
    // ---- stage patch: 864 16B-units (432 hi + 432 lo)
    for (int u = t; u < 864; u += 256) {
      int half = (u >= 432) ? 1 : 0;
      int r2 = u - half * 432;
      int unit = r2 & 3, slot = r2 >> 2;
      int pr = slot / 18, pc = slot - pr * 18;
      int r = h0 - 1 + pr, c = w0 - 1 + pc;
      uint4 v = make_uint4(0u, 0u, 0u, 0u);
      if (((unsigned)r < 80u) && ((unsigned)c < 80u)) {
        const char* src = (half ? xTlb : xTb) + (((r * 80 + c) << 8) + cc * 64 + unit * 16);
        v = *(const uint4*)src;
      }
      *(uint4*)(patch + half * 8640 + slot * 80 + unit * 16) = v;
    }
    __syncthreads();                               // patch ready
#pragma unroll
    for (int tap = 0; tap < 9; ++tap) {
      int dh = tap / 3, dw = tap - dh * 3;         // 0..2
      int lo = (((wave + dh) * 18) + (n16 + dw)) * 80 + koct * 16;
      short8 bh = *(const short8*)(patch + lo);
      short8 bl = *(const short8*)(patch + 8640 + lo);
      short8 ah = *(const short8*)(apwh + ((tap * 4 + cc) * 64 + lane) * 8);
      short8 al = *(const short8*)(apwl + ((tap * 4 + cc) * 64 + lane) * 8);
      acc = __builtin_amdgcn_mfma_f32_16x16x32_bf16(ah, bh, acc, 0, 0, 0);
      acc = __builtin_amdgcn_mfma_f32_16x16x32_bf16(ah, bl, acc, 0, 0, 0);
      acc = __builtin_amdgcn_mfma_f32_16x16x32_bf16(al, bh, acc, 0, 0, 0);
    }
  }

  int quad = lane >> 4;
#pragma unroll
  for (int r = 0; r < 4; ++r) {
    int row = quad * 4 + r;
    if (row < 10) sOff[wave][row][n16] = acc[r];
  }
  __syncthreads();

  for (int task = t; task < 320; task += 256) {
    int wv = task / 80, rem2 = task - wv * 80, k = rem2 >> 4, n = rem2 & 15;
    int h2 = h0 + wv, w2 = w0 + n;
    int p2 = h2 * 80 + w2;
    float px = sOff[wv][k][n] + pb[k] + (float)(h2 + (k >> 1));
    float py = sOff[wv][5 + k][n] + pb[5 + k] + (float)(w2 + (k & 1));
    float pf = floorf(px), qf = floorf(py);
    float x0 = fminf(fmaxf(pf, 0.f), 79.f);
    float x1 = fminf(fmaxf(pf + 1.f, 0.f), 79.f);
    float y0 = fminf(fmaxf(qf, 0.f), 79.f);
    float y1 = fminf(fmaxf(qf + 1.f, 0.f), 79.f);
    float pxc = fminf(fmaxf(px, 0.f), 79.f);
    float pyc = fminf(fmaxf(py, 0.f), 79.f);
    float wx0 = 1.f + (x0 - pxc), wx1 = 1.f - (x1 - pxc);
    float wy0 = 1.f + (y0 - pyc), wy1 = 1.f - (y1 - pyc);
    int ix0 = (int)x0, ix1 = (int)x1, iy0 = (int)y0, iy1 = (int)y1;
    int g = (b * NP + k) * HW + p2;
    idx4[g] = make_int4((ix0 * 80 + iy0) << 8, (ix1 * 80 + iy1) << 8,
                        (ix0 * 80 + iy1) << 8, (ix1 * 80 + iy0) << 8);
    wgt4[g] = make_float4(wx0 * wy0, wx1 * wy1, wx0 * wy1, wx1 * wy0);
  }
}

// ---- K3: R7-verified gather + MFMA GEMM + BN + SiLU ------------------------
// Block: M=256, N=32 px; 1600 blocks; 4 waves. Wave w stages (grp=w&1,
// cchalf=w>>1); loads issue before compute(k); weighted-sum + ds_write after.
__device__ __forceinline__ void stage_load(
    const char* xTb, const int4* __restrict__ idx4, const float4* __restrict__ wgt4,
    size_t sampBase, int k, int grp, int cchalf, int lane,
    uint4 q[2][4], float4& wg) {
  int p4 = lane & 15, j = lane >> 4;
  size_t g = sampBase + (size_t)k * HW + grp * 16 + p4;
  int4 id = idx4[g];
  wg = wgt4[g];
  int cj = j * 16;
#pragma unroll
  for (int hf = 0; hf < 2; ++hf) {
    int cb = (cchalf * 2 + hf) * 64 + cj;
    q[hf][0] = *(const uint4*)(xTb + id.x + cb);
    q[hf][1] = *(const uint4*)(xTb + id.y + cb);
    q[hf][2] = *(const uint4*)(xTb + id.z + cb);
    q[hf][3] = *(const uint4*)(xTb + id.w + cb);
  }
}

__device__ __forceinline__ void stage_store(
    unsigned short* BsBuf, int grp, int cchalf, int lane,
    uint4 q[2][4], float4 wg) {
#pragma unroll
  for (int hf = 0; hf < 2; ++hf) {
    int cc = cchalf * 2 + hf;
    const unsigned short* a0 = (const unsigned short*)&q[hf][0];
    const unsigned short* a1 = (const unsigned short*)&q[hf][1];
    const unsigned short* a2 = (const unsigned short*)&q[hf][2];
    const unsigned short* a3 = (const unsigned short*)&q[hf][3];
    union { uint4 v; unsigned short u[8]; } rr;
#pragma unroll
    for (int e = 0; e < 8; ++e) {
      float f = wg.x * bfu2f(a0[e]) + wg.y * bfu2f(a1[e])
              + wg.z * bfu2f(a2[e]) + wg.w * bfu2f(a3[e]);
      rr.u[e] = f2bf(f);
    }
    *(uint4*)&BsBuf[((cc * 2 + grp) * 64 + lane) * 8] = rr.v;
  }
}

__global__ __launch_bounds__(256) void k_main(
    const unsigned short* __restrict__ xT,
    const unsigned short* __restrict__ acw,
    const int4* __restrict__ idx4, const float4* __restrict__ wgt4,
    const float* __restrict__ bns, const float* __restrict__ bnt,
    float* __restrict__ out) {
  __shared__ unsigned short Bs[2][8 * 64 * 8];     // 2 x 8 KB

  int t = threadIdx.x;
  int gp0 = blockIdx.x * 32;
  int b = gp0 / HW, pbase = gp0 - b * HW;
  int wave = t >> 6, lane = t & 63;
  int grp = wave & 1, cchalf = wave >> 1;
  const char* xTb = (const char*)xT + (size_t)b * HW * 256;
  size_t sampBase = (size_t)b * NP * HW + pbase;

  f32x4 acc[4][2];
#pragma unroll
  for (int mt = 0; mt < 4; ++mt)
#pragma unroll
    for (int nt = 0; nt < 2; ++nt) acc[mt][nt] = (f32x4)(0.f);

  uint4 pf[2][4];
  float4 pwg;
  stage_load(xTb, idx4, wgt4, sampBase, 0, grp, cchalf, lane, pf, pwg);
  stage_store(Bs[0], grp, cchalf, lane, pf, pwg);

#pragma unroll
  for (int k = 0; k < NP; ++k) {
    __syncthreads();                    // Bs[k&1] staged for all waves
    if (k + 1 < NP)
      stage_load(xTb, idx4, wgt4, sampBase, k + 1, grp, cchalf, lane, pf, pwg);
    const unsigned short* Bk = Bs[k & 1];
#pragma unroll
    for (int cc = 0; cc < 4; ++cc) {
      short8 bfr[2];
#pragma unroll
      for (int nt = 0; nt < 2; ++nt)
        bfr[nt] = *(const short8*)&Bk[((cc * 2 + nt) * 64 + lane) * 8];
      const unsigned short* ab =
          acw + (size_t)((((k * 4 + cc) * 16) + wave * 4) * 64 + lane) * 8;
#pragma unroll
      for (int mt = 0; mt < 4; ++mt) {
        short8 a = *(const short8*)(ab + mt * 64 * 8);
#pragma unroll
        for (int nt = 0; nt < 2; ++nt)
          acc[mt][nt] = __builtin_amdgcn_mfma_f32_16x16x32_bf16(
              a, bfr[nt], acc[mt][nt], 0, 0, 0);
      }
    }
    if (k + 1 < NP)
      stage_store(Bs[(k + 1) & 1], grp, cchalf, lane, pf, pwg);
  }

  // ---- epilogue: BN + SiLU
  int quad = lane >> 4, col = lane & 15;
#pragma unroll
  for (int mt = 0; mt < 4; ++mt) {
    int m0 = wave * 64 + mt * 16 + quad * 4;
#pragma unroll
    for (int r = 0; r < 4; ++r) {
      int m = m0 + r;
      float s = bns[m], sh = bnt[m];
      float* op = out + ((size_t)(b * C2 + m)) * HW + pbase;
#pragma unroll
      for (int nt = 0; nt < 2; ++nt) {
        float y = fmaf(acc[mt][nt][r], s, sh);
        op[nt * 16 + col] = y * (1.f / (1.f + __expf(-y)));
      }
    }
  }
}

extern "C" void kernel_launch(void* const* d_in, const int* in_sizes, int n_in,
                              void* d_out, int out_size, void* d_ws, size_t ws_size,
                              hipStream_t stream) {
  const float* x  = (const float*)d_in[0];
  const float* pw = (const float*)d_in[1];
  const float* pb = (const float*)d_in[2];
  const float* cw = (const float*)d_in[3];
  const float* bg = (const float*)d_in[4];
  const float* bb = (const float*)d_in[5];
  const float* bm = (const float*)d_in[6];
  const float* bv = (const float*)d_in[7];
  float* out = (float*)d_out;

  char* ws = (char*)d_ws;
  int4*           idx4 = (int4*)(ws + WS_IDX4);
  float4*         wgt4 = (float4*)(ws + WS_WGT4);
  unsigned short* xT   = (unsigned short*)(ws + WS_XT);
  unsigned short* xTlo = (unsigned short*)(ws + WS_XTLO);
  unsigned short* acw  = (unsigned short*)(ws + WS_ACW);
  unsigned short* apwh = (unsigned short*)(ws + WS_APWH);
  unsigned short* apwl = (unsigned short*)(ws + WS_APWL);
  float*          bns  = (float*)(ws + WS_BNS);
  float*          bnt  = (float*)(ws + WS_BNT);

  k_prep<<<2312, 256, 0, stream>>>(x, cw, pw, bg, bb, bm, bv,
                                   xT, xTlo, acw, apwh, apwl, bns, bnt);
  k_offset<<<800, 256, 0, stream>>>(xT, xTlo, apwh, apwl, pb, idx4, wgt4);
  k_main<<<1600, 256, 0, stream>>>(xT, acw, idx4, wgt4, bns, bnt, out);
}